// Round 14
// baseline (353.724 us; speedup 1.0000x reference)
//
#include <hip/hip_runtime.h>
#include <hip/hip_fp16.h>
#include <math.h>

#define N_NODES 50000
#define N_EDGES 800000
#define E_TOT   (N_EDGES + N_NODES)   // 850000, self-loops appended
#define IN_DIM  32
#define HID     96
#define NEG_SLOPE 0.2f
#define MAXD    128                   // LDS chunk per wave (per-chunk staging)
#define SCAN_BS 1024
#define N_SCAN_BLOCKS ((N_NODES + SCAN_BS - 1) / SCAN_BS)   // 49
#define FILL_PASSES 8
#define FILL_WIN (N_NODES / FILL_PASSES)   // 6250
#define NODE_BLOCKS (N_NODES / 4)          // 12500 blocks of 4 waves/nodes
#define PREP_BLOCKS ((N_NODES * 32) / 256) // 6250
#define WT_BLOCKS (((HID * HID) + 255) / 256) // 36

typedef _Float16 half8v __attribute__((ext_vector_type(8)));
typedef float    float4v __attribute__((ext_vector_type(4)));

static inline int cdiv(long long a, int b) { return (int)((a + b - 1) / b); }

// ---------------- dispatch 1: hist + layer0 prep + weight transposes (disjoint data) ----

__global__ __launch_bounds__(256) void hist_prep_kernel(
    const int* __restrict__ ei, unsigned* __restrict__ deg, int nb_e,
    const float* __restrict__ x, const float* __restrict__ W0,
    const float* __restrict__ as0, const float* __restrict__ ad0,
    __half* __restrict__ xh, float* __restrict__ es, float* __restrict__ ed,
    const float* __restrict__ W1, const float* __restrict__ W2,
    __half* __restrict__ WT0, __half* __restrict__ WT1, __half* __restrict__ WT2) {
    if ((int)blockIdx.x < nb_e) {
        // hist: single pass — atomics into 200 KB DEG resolve in cache
        int e = blockIdx.x * 256 + threadIdx.x;
        if (e >= E_TOT) return;
        int d = (e < N_EDGES) ? ei[N_EDGES + e] : (e - N_EDGES);
        atomicAdd(deg + d, 1u);
        return;
    }
    if ((int)blockIdx.x >= nb_e + PREP_BLOCKS) {
        // weight transposes: WT1/WT2 (96x96), WT0 (96x32)
        int i = (blockIdx.x - nb_e - PREP_BLOCKS) * 256 + threadIdx.x;
        if (i < HID * HID) {
            int n = i / HID, k = i - n * HID;
            WT1[i] = __float2half(W1[k * HID + n]);
            WT2[i] = __float2half(W2[k * HID + n]);
        }
        if (i < HID * IN_DIM) {
            int n = i >> 5, k = i & 31;
            WT0[i] = __float2half(W0[k * HID + n]);
        }
        return;
    }
    // layer-0 prep: u projections + es/ed + x fp16 cast
    __shared__ float s_us[32], s_ud[32];
    if (threadIdx.x < 64) {
        int k = threadIdx.x & 31;
        int sel = threadIdx.x >> 5;
        const float* a = sel ? ad0 : as0;
        float acc = 0.f;
        #pragma unroll 8
        for (int c = 0; c < HID; ++c) acc += W0[k * HID + c] * a[c];
        if (sel) s_ud[k] = acc; else s_us[k] = acc;
    }
    __syncthreads();
    int idx = (blockIdx.x - nb_e) * 256 + threadIdx.x;
    int node = idx >> 5;
    int k = threadIdx.x & 31;
    float xv = x[(size_t)node * 32 + k];
    float xnb = __shfl_xor(xv, 1);
    if ((k & 1) == 0) {
        __half2 h2v = __floats2half2_rn(xv, xnb);
        ((__half2*)xh)[((size_t)node * 32 + k) >> 1] = h2v;
    }
    float ps = xv * s_us[k], pd = xv * s_ud[k];
    #pragma unroll
    for (int o = 16; o; o >>= 1) {
        ps += __shfl_xor(ps, o);
        pd += __shfl_xor(pd, o);
    }
    if (k == 0) { es[node] = ps; ed[node] = pd; }
}

// ---------------- dispatch 2: full scan in one kernel (49 blocks, internal barrier) -----
__global__ __launch_bounds__(SCAN_BS) void scan_all_kernel(
    const unsigned* __restrict__ deg, unsigned* __restrict__ rs,
    unsigned* __restrict__ bsums, unsigned* __restrict__ done,
    unsigned* __restrict__ wptr, int n) {
    __shared__ unsigned buf[SCAN_BS];
    __shared__ unsigned s_off;
    int i = blockIdx.x * SCAN_BS + threadIdx.x;
    unsigned v = (i < n) ? deg[i] : 0u;
    buf[threadIdx.x] = v;
    __syncthreads();
    for (int o = 1; o < SCAN_BS; o <<= 1) {
        unsigned t = (threadIdx.x >= (unsigned)o) ? buf[threadIdx.x - o] : 0u;
        __syncthreads();
        buf[threadIdx.x] += t;
        __syncthreads();
    }
    unsigned excl = buf[threadIdx.x] - v;
    if (threadIdx.x == SCAN_BS - 1) bsums[blockIdx.x] = buf[SCAN_BS - 1];
    __threadfence();
    __syncthreads();
    if (threadIdx.x == 0) {
        atomicAdd(done, 1u);
        while (atomicAdd(done, 0u) < (unsigned)N_SCAN_BLOCKS) { }   // 49 blocks all resident
    }
    __syncthreads();
    __threadfence();
    if (threadIdx.x < 64) {
        unsigned pv = ((int)threadIdx.x < (int)blockIdx.x) ? bsums[threadIdx.x] : 0u;
        #pragma unroll
        for (int o = 32; o; o >>= 1) pv += __shfl_xor(pv, o);
        if (threadIdx.x == 0) s_off = pv;
    }
    __syncthreads();
    unsigned off = s_off;
    if (i < n) {
        unsigned r = excl + off;
        rs[i] = r;
        wptr[i] = r;
    }
    if (i == n) rs[n] = E_TOT;
}

// ---------------- dispatch 3: XCD-pinned windowed fill --------------------------------
__global__ void fill_win_kernel(const int* __restrict__ ei, unsigned* __restrict__ wptr,
                                int* __restrict__ srcs) {
    int pass = blockIdx.x & 7;          // XCD-pinned pass (round-robin block->XCD)
    int eb   = blockIdx.x >> 3;
    int e = eb * 256 + threadIdx.x;
    if (e >= E_TOT) return;
    int lo = pass * FILL_WIN;
    int d = (e < N_EDGES) ? ei[N_EDGES + e] : (e - N_EDGES);
    if ((unsigned)(d - lo) >= (unsigned)FILL_WIN) return;
    int s = (e < N_EDGES) ? ei[e] : d;
    unsigned pos = atomicAdd(wptr + d, 1u);
    srcs[pos] = s;
}

// ---------------- layer 0: gather 32-dim fp16 x -> AGG (N*32 fp32) ----------------------
__global__ __launch_bounds__(256) void aggregate32_kernel(
    const unsigned* __restrict__ rs, const int* __restrict__ srcs,
    const float* __restrict__ es, const float* __restrict__ ed,
    const __half* __restrict__ xh, float* __restrict__ agg) {
    __shared__ uint2 sh[4][MAXD];
    int node = (int)((blockIdx.x * (long long)blockDim.x + threadIdx.x) >> 6);
    int lane = threadIdx.x & 63;
    int wv = threadIdx.x >> 6;
    int grp = lane >> 3, lin = lane & 7;
    unsigned row = rs[node];
    int deg = (int)(rs[node + 1] - row);
    float edv = ed[node];

    float lsum = 0.f;
    float4 acc = {0.f, 0.f, 0.f, 0.f};
    const uint2* x2 = (const uint2*)xh;   // row = 8 uint2

    for (int base = 0; base < deg; base += MAXD) {
        int cnt = min(MAXD, deg - base);
        for (int j = lane; j < cnt; j += 64) {
            int s = srcs[row + base + j];
            float v = es[s] + edv;
            v = v > 0.f ? v : NEG_SLOPE * v;
            float e = __expf(v);
            uint2 p; p.x = (unsigned)s; p.y = __float_as_uint(e);
            sh[wv][j] = p;
            lsum += e;
        }
        int jb = 0;
        for (; jb + 16 <= cnt; jb += 16) {
            uint2 pa = sh[wv][jb + grp];
            uint2 pb = sh[wv][jb + 8 + grp];
            uint2 qa = x2[(size_t)pa.x * 8 + lin];
            uint2 qb = x2[(size_t)pb.x * 8 + lin];
            float ea = __uint_as_float(pa.y), eb = __uint_as_float(pb.y);
            float2 fa0 = __half22float2(*(__half2*)&qa.x);
            float2 fa1 = __half22float2(*(__half2*)&qa.y);
            float2 fb0 = __half22float2(*(__half2*)&qb.x);
            float2 fb1 = __half22float2(*(__half2*)&qb.y);
            acc.x += ea * fa0.x + eb * fb0.x; acc.y += ea * fa0.y + eb * fb0.y;
            acc.z += ea * fa1.x + eb * fb1.x; acc.w += ea * fa1.y + eb * fb1.y;
        }
        for (; jb < cnt; jb += 8) {
            int r = jb + grp;
            if (r < cnt) {
                uint2 p = sh[wv][r];
                float e = __uint_as_float(p.y);
                uint2 q = x2[(size_t)p.x * 8 + lin];
                float2 f0 = __half22float2(*(__half2*)&q.x);
                float2 f1 = __half22float2(*(__half2*)&q.y);
                acc.x += e * f0.x; acc.y += e * f0.y;
                acc.z += e * f1.x; acc.w += e * f1.y;
            }
        }
    }
    #pragma unroll
    for (int o = 32; o; o >>= 1) lsum += __shfl_xor(lsum, o);
    #pragma unroll
    for (int o = 8; o <= 32; o <<= 1) {
        acc.x += __shfl_xor(acc.x, o);
        acc.y += __shfl_xor(acc.y, o);
        acc.z += __shfl_xor(acc.z, o);
        acc.w += __shfl_xor(acc.w, o);
    }
    if (grp == 0) {
        float inv = 1.f / lsum;
        float4 o4; o4.x = acc.x * inv; o4.y = acc.y * inv; o4.z = acc.z * inv; o4.w = acc.w * inv;
        ((float4*)agg)[(size_t)node * 8 + lin] = o4;
    }
}

// ---------------- layer 0 GEMM + layer 1 GEMM fused (per-16-node tile, MFMA) ------------
// GEMM0: X16A_tile = relu(AGG_tile @ W0 + b0) via one K=32 MFMA per N-tile; tile round-
// trips through LDS (wave-synchronous) to convert C-layout -> A-layout; also stored to
// X16A global (residual for layer 1). GEMM1: K=96 vs WT1, fused es/ed scores.
__global__ __launch_bounds__(256) void mfma_l01_kernel(
    const float* __restrict__ agg, const __half* __restrict__ wt0,
    const float* __restrict__ b0, const __half* __restrict__ wt1,
    const float* __restrict__ a_s, const float* __restrict__ a_d,
    __half* __restrict__ h, float* __restrict__ es, float* __restrict__ ed,
    __half* __restrict__ x16a) {
    __shared__ __align__(16) __half tile[4][16 * 96];
    int wid = (int)((blockIdx.x * 256 + threadIdx.x) >> 6);
    if (wid >= N_NODES / 16) return;    // 3125 M-tiles
    int lane = threadIdx.x & 63;
    int wv = threadIdx.x >> 6;
    int col = lane & 15, quad = lane >> 4;
    int m0 = wid * 16;

    // ---- GEMM0: A = AGG[m0+col][quad*8 .. +7] (fp32 -> fp16), B = WT0 rows ----
    half8v a0;
    {
        const float4* ar = (const float4*)(agg + (size_t)(m0 + col) * 32 + quad * 8);
        float4 f0 = ar[0], f1 = ar[1];
        a0[0] = (_Float16)f0.x; a0[1] = (_Float16)f0.y; a0[2] = (_Float16)f0.z; a0[3] = (_Float16)f0.w;
        a0[4] = (_Float16)f1.x; a0[5] = (_Float16)f1.y; a0[6] = (_Float16)f1.z; a0[7] = (_Float16)f1.w;
    }
    #pragma unroll
    for (int t = 0; t < 6; ++t) {
        half8v bfrag = *(const half8v*)(wt0 + (size_t)(t * 16 + col) * 32 + quad * 8);
        float4v c0 = (float4v){0.f, 0.f, 0.f, 0.f};
        c0 = __builtin_amdgcn_mfma_f32_16x16x32_f16(a0, bfrag, c0, 0, 0, 0);
        int n = t * 16 + col;
        float bv = b0[n];
        #pragma unroll
        for (int r = 0; r < 4; ++r) {
            int m = quad * 4 + r;
            float v = fmaxf(c0[r] + bv, 0.f);
            __half hv = __float2half(v);
            tile[wv][m * 96 + n] = hv;
            x16a[(size_t)(m0 + m) * 96 + n] = hv;
        }
    }
    // same-wave LDS RAW (full 16x96 tile produced by this wave) — lgkmcnt-ordered

    // ---- GEMM1: A from LDS tile, B = WT1, K=96 ----
    float4v acc[6];
    #pragma unroll
    for (int t = 0; t < 6; ++t) acc[t] = (float4v){0.f, 0.f, 0.f, 0.f};
    #pragma unroll
    for (int ks = 0; ks < 3; ++ks) {
        half8v afrag = *(const half8v*)(&tile[wv][(lane & 15) * 96 + ks * 32 + quad * 8]);
        #pragma unroll
        for (int t = 0; t < 6; ++t) {
            half8v bfrag = *(const half8v*)(wt1 + (size_t)(t * 16 + col) * 96 + ks * 32 + quad * 8);
            acc[t] = __builtin_amdgcn_mfma_f32_16x16x32_f16(afrag, bfrag, acc[t], 0, 0, 0);
        }
    }

    float ps0 = 0.f, ps1 = 0.f, ps2 = 0.f, ps3 = 0.f;
    float pd0 = 0.f, pd1 = 0.f, pd2 = 0.f, pd3 = 0.f;
    #pragma unroll
    for (int t = 0; t < 6; ++t) {
        int ch = t * 16 + col;
        float sa = a_s[ch], sd = a_d[ch];
        float v0 = acc[t][0], v1 = acc[t][1], v2 = acc[t][2], v3 = acc[t][3];
        size_t rbase = (size_t)(m0 + quad * 4) * 96 + ch;
        h[rbase]       = __float2half(v0);
        h[rbase + 96]  = __float2half(v1);
        h[rbase + 192] = __float2half(v2);
        h[rbase + 288] = __float2half(v3);
        ps0 += v0 * sa; ps1 += v1 * sa; ps2 += v2 * sa; ps3 += v3 * sa;
        pd0 += v0 * sd; pd1 += v1 * sd; pd2 += v2 * sd; pd3 += v3 * sd;
    }
    #pragma unroll
    for (int o = 1; o < 16; o <<= 1) {
        ps0 += __shfl_xor(ps0, o); ps1 += __shfl_xor(ps1, o);
        ps2 += __shfl_xor(ps2, o); ps3 += __shfl_xor(ps3, o);
        pd0 += __shfl_xor(pd0, o); pd1 += __shfl_xor(pd1, o);
        pd2 += __shfl_xor(pd2, o); pd3 += __shfl_xor(pd3, o);
    }
    if (col == 0) {
        int nb = m0 + quad * 4;
        es[nb] = ps0; es[nb + 1] = ps1; es[nb + 2] = ps2; es[nb + 3] = ps3;
        ed[nb] = pd0; ed[nb + 1] = pd1; ed[nb + 2] = pd2; ed[nb + 3] = pd3;
    }
}

// ---------------- layer 2: MFMA GEMM (fp16 in, fp16 h out) with fused scores ------------
__global__ __launch_bounds__(256) void mfma_gemm96_kernel(
    const __half* __restrict__ x16, const __half* __restrict__ wt,
    const float* __restrict__ a_s, const float* __restrict__ a_d,
    __half* __restrict__ h, float* __restrict__ es, float* __restrict__ ed) {
    int wid = (int)((blockIdx.x * 256 + threadIdx.x) >> 6);
    if (wid >= N_NODES / 16) return;    // 3125 M-tiles
    int lane = threadIdx.x & 63;
    int col = lane & 15, quad = lane >> 4;
    int m0 = wid * 16;
    const __half* arow = x16 + (size_t)(m0 + col) * 96 + quad * 8;
    const __half* brow = wt + (size_t)col * 96 + quad * 8;

    float4v acc[6];
    #pragma unroll
    for (int t = 0; t < 6; ++t) acc[t] = (float4v){0.f, 0.f, 0.f, 0.f};

    #pragma unroll
    for (int ks = 0; ks < 3; ++ks) {
        half8v afrag = *(const half8v*)(arow + ks * 32);
        #pragma unroll
        for (int t = 0; t < 6; ++t) {
            half8v bfrag = *(const half8v*)(brow + (size_t)t * 16 * 96 + ks * 32);
            acc[t] = __builtin_amdgcn_mfma_f32_16x16x32_f16(afrag, bfrag, acc[t], 0, 0, 0);
        }
    }

    float ps0 = 0.f, ps1 = 0.f, ps2 = 0.f, ps3 = 0.f;
    float pd0 = 0.f, pd1 = 0.f, pd2 = 0.f, pd3 = 0.f;
    #pragma unroll
    for (int t = 0; t < 6; ++t) {
        int ch = t * 16 + col;
        float sa = a_s[ch], sd = a_d[ch];
        float v0 = acc[t][0], v1 = acc[t][1], v2 = acc[t][2], v3 = acc[t][3];
        size_t rbase = (size_t)(m0 + quad * 4) * 96 + ch;
        h[rbase]       = __float2half(v0);
        h[rbase + 96]  = __float2half(v1);
        h[rbase + 192] = __float2half(v2);
        h[rbase + 288] = __float2half(v3);
        ps0 += v0 * sa; ps1 += v1 * sa; ps2 += v2 * sa; ps3 += v3 * sa;
        pd0 += v0 * sd; pd1 += v1 * sd; pd2 += v2 * sd; pd3 += v3 * sd;
    }
    #pragma unroll
    for (int o = 1; o < 16; o <<= 1) {
        ps0 += __shfl_xor(ps0, o); ps1 += __shfl_xor(ps1, o);
        ps2 += __shfl_xor(ps2, o); ps3 += __shfl_xor(ps3, o);
        pd0 += __shfl_xor(pd0, o); pd1 += __shfl_xor(pd1, o);
        pd2 += __shfl_xor(pd2, o); pd3 += __shfl_xor(pd3, o);
    }
    if (col == 0) {
        int nb = m0 + quad * 4;
        es[nb] = ps0; es[nb + 1] = ps1; es[nb + 2] = ps2; es[nb + 3] = ps3;
        ed[nb] = pd0; ed[nb + 1] = pd1; ed[nb + 2] = pd2; ed[nb + 3] = pd3;
    }
}

// ---------------- fused softmax + gather (96ch), 16/8/2-row pipeline ---------------------
__global__ __launch_bounds__(256) void aggregate96_kernel(
    const unsigned* __restrict__ rs, const int* __restrict__ srcs,
    const float* __restrict__ es, const float* __restrict__ ed,
    const __half* __restrict__ h, const float* __restrict__ b,
    const __half* __restrict__ res16, __half* __restrict__ out16,
    const float* __restrict__ Wf, float* __restrict__ hfin, int do_relu) {
    __shared__ uint2 sh[4][MAXD];
    int node = (int)((blockIdx.x * (long long)blockDim.x + threadIdx.x) >> 6);
    int lane = threadIdx.x & 63;
    int wv = threadIdx.x >> 6;
    int half_ = lane >> 5, lin = lane & 31;
    unsigned row = rs[node];
    int deg = (int)(rs[node + 1] - row);
    float edv = ed[node];

    float lsum = 0.f;
    float4 acc = {0.f, 0.f, 0.f, 0.f};
    const uint2* h4 = (const uint2*)h;    // row = 24 uint2 (96 halves)
    bool act = (lin < 24);

    for (int base = 0; base < deg; base += MAXD) {
        int cnt = min(MAXD, deg - base);
        for (int j = lane; j < cnt; j += 64) {
            int s = srcs[row + base + j];
            float v = es[s] + edv;
            v = v > 0.f ? v : NEG_SLOPE * v;
            float e = __expf(v);
            uint2 p; p.x = (unsigned)s; p.y = __float_as_uint(e);
            sh[wv][j] = p;   // same-wave RAW, ordered by lgkmcnt
            lsum += e;
        }
        int jb = 0;
        for (; jb + 16 <= cnt; jb += 16) {
            uint2 pp[8];
            #pragma unroll
            for (int u = 0; u < 8; ++u) pp[u] = sh[wv][jb + 2 * u + half_];
            if (act) {
                uint2 qq[8];
                #pragma unroll
                for (int u = 0; u < 8; ++u) qq[u] = h4[(size_t)pp[u].x * 24 + lin];
                #pragma unroll
                for (int u = 0; u < 8; ++u) {
                    float e = __uint_as_float(pp[u].y);
                    float2 f0 = __half22float2(*(__half2*)&qq[u].x);
                    float2 f1 = __half22float2(*(__half2*)&qq[u].y);
                    acc.x += e * f0.x; acc.y += e * f0.y;
                    acc.z += e * f1.x; acc.w += e * f1.y;
                }
            }
        }
        for (; jb + 8 <= cnt; jb += 8) {
            uint2 pp[4];
            #pragma unroll
            for (int u = 0; u < 4; ++u) pp[u] = sh[wv][jb + 2 * u + half_];
            if (act) {
                uint2 qq[4];
                #pragma unroll
                for (int u = 0; u < 4; ++u) qq[u] = h4[(size_t)pp[u].x * 24 + lin];
                #pragma unroll
                for (int u = 0; u < 4; ++u) {
                    float e = __uint_as_float(pp[u].y);
                    float2 f0 = __half22float2(*(__half2*)&qq[u].x);
                    float2 f1 = __half22float2(*(__half2*)&qq[u].y);
                    acc.x += e * f0.x; acc.y += e * f0.y;
                    acc.z += e * f1.x; acc.w += e * f1.y;
                }
            }
        }
        for (; jb < cnt; jb += 2) {
            int r = jb + half_;
            if (act && r < cnt) {
                uint2 p = sh[wv][r];
                float e = __uint_as_float(p.y);
                uint2 q = h4[(size_t)p.x * 24 + lin];
                float2 f0 = __half22float2(*(__half2*)&q.x);
                float2 f1 = __half22float2(*(__half2*)&q.y);
                acc.x += e * f0.x; acc.y += e * f0.y;
                acc.z += e * f1.x; acc.w += e * f1.y;
            }
        }
    }
    #pragma unroll
    for (int o = 32; o; o >>= 1) lsum += __shfl_xor(lsum, o);
    acc.x += __shfl_xor(acc.x, 32);
    acc.y += __shfl_xor(acc.y, 32);
    acc.z += __shfl_xor(acc.z, 32);
    acc.w += __shfl_xor(acc.w, 32);

    float pfin = 0.f;
    if (half_ == 0 && lin < 24) {
        float inv = 1.f / lsum;
        float4 bb = ((const float4*)b)[lin];
        float4 v;
        v.x = acc.x * inv + bb.x; v.y = acc.y * inv + bb.y;
        v.z = acc.z * inv + bb.z; v.w = acc.w * inv + bb.w;
        if (res16) {
            uint2 rr = ((const uint2*)res16)[(size_t)node * 24 + lin];
            float2 r0 = __half22float2(*(__half2*)&rr.x);
            float2 r1 = __half22float2(*(__half2*)&rr.y);
            v.x += r0.x; v.y += r0.y; v.z += r1.x; v.w += r1.y;
        }
        if (do_relu) {
            v.x = fmaxf(v.x, 0.f); v.y = fmaxf(v.y, 0.f);
            v.z = fmaxf(v.z, 0.f); v.w = fmaxf(v.w, 0.f);
        }
        if (out16) {
            __half2 q0 = __floats2half2_rn(v.x, v.y), q1 = __floats2half2_rn(v.z, v.w);
            uint2 st; st.x = *(unsigned*)&q0; st.y = *(unsigned*)&q1;
            ((uint2*)out16)[(size_t)node * 24 + lin] = st;
        }
        if (hfin) {
            float4 wf = ((const float4*)Wf)[lin];
            pfin = v.x * wf.x + v.y * wf.y + v.z * wf.z + v.w * wf.w;
        }
    }
    if (hfin) {
        #pragma unroll
        for (int o = 1; o < 32; o <<= 1) pfin += __shfl_xor(pfin, o);
        if (lane == 0) hfin[node] = pfin;
    }
}

// ---------------- final dout=1 aggregate: everything from hfin (single gather) -----------
__global__ __launch_bounds__(256) void aggregate1_kernel(
    const unsigned* __restrict__ rs, const int* __restrict__ srcs,
    const float* __restrict__ hfin, const float* __restrict__ asf,
    const float* __restrict__ adf, const float* __restrict__ bf,
    float* __restrict__ out) {
    int node = (int)((blockIdx.x * (long long)blockDim.x + threadIdx.x) >> 6);
    int lane = threadIdx.x & 63;
    unsigned row = rs[node];
    int deg = (int)(rs[node + 1] - row);
    float as0 = asf[0], ad0 = adf[0];
    float edv = hfin[node] * ad0;

    float lsum = 0.f, acc = 0.f;
    for (int j = lane; j < deg; j += 64) {
        int s = srcs[row + j];
        float hs = hfin[s];
        float v = as0 * hs + edv;
        v = v > 0.f ? v : NEG_SLOPE * v;
        float ex = __expf(v);
        lsum += ex;
        acc += ex * hs;
    }
    #pragma unroll
    for (int o = 32; o; o >>= 1) {
        lsum += __shfl_xor(lsum, o);
        acc  += __shfl_xor(acc, o);
    }
    if (lane == 0) out[node] = acc / lsum + bf[0];
}

// ---------------- host-side orchestration ----------------

extern "C" void kernel_launch(void* const* d_in, const int* in_sizes, int n_in,
                              void* d_out, int out_size, void* d_ws, size_t ws_size,
                              hipStream_t stream) {
    const float* x  = (const float*)d_in[0];
    const int*   ei = (const int*)d_in[1];
    const float* W0 = (const float*)d_in[3];
    const float* as0 = (const float*)d_in[4];
    const float* ad0 = (const float*)d_in[5];
    const float* b0 = (const float*)d_in[6];
    const float* W1 = (const float*)d_in[7];
    const float* as1 = (const float*)d_in[8];
    const float* ad1 = (const float*)d_in[9];
    const float* b1 = (const float*)d_in[10];
    const float* W2 = (const float*)d_in[11];
    const float* as2 = (const float*)d_in[12];
    const float* ad2 = (const float*)d_in[13];
    const float* b2 = (const float*)d_in[14];
    const float* Wf = (const float*)d_in[15];
    const float* asf = (const float*)d_in[16];
    const float* adf = (const float*)d_in[17];
    const float* bf = (const float*)d_in[18];

    float* out = (float*)d_out;  // 50000 floats

    // workspace carve-up
    float* Hf = (float*)d_ws;                    // N*96 float slot: DEG/BS/DONE early, H16 later
    __half* H16 = (__half*)Hf;
    float* ES = Hf + (long long)N_NODES * HID;   // N
    float* ED = ES + N_NODES;                    // N
    unsigned* RS   = (unsigned*)(ED + N_NODES);  // N+1
    unsigned* WPTR = RS + (N_NODES + 1);         // N
    int* SRCS = (int*)(WPTR + N_NODES);          // E_TOT
    __half* XH  = (__half*)(SRCS + E_TOT + 2);   // N*32 halves (dedicated — no alias w/ DEG)
    __half* X16A = XH + (size_t)N_NODES * IN_DIM;  // N*96 halves
    __half* X16B = X16A + (size_t)N_NODES * HID;   // N*96 halves
    __half* WT0 = X16B + (size_t)N_NODES * HID;    // 96*32 halves
    __half* WT1 = WT0 + HID * IN_DIM;              // 96*96 halves
    __half* WT2 = WT1 + HID * HID;                 // 96*96 halves
    float* HFIN = (float*)(WT2 + HID * HID);       // N floats
    float* AGG  = HFIN + N_NODES;                  // N*32 fp32
    unsigned* DEG = (unsigned*)Hf;               // CSR temps aliased onto Hf (pre-MFMA)
    unsigned* BS  = DEG + N_NODES;               // 49
    unsigned* DONE = BS + 64;                    // 1

    const int nb_e = cdiv(E_TOT, 256);

    // ---- CSR build + layer-0 prep, minimal dispatches ----
    hipMemsetAsync(DEG, 0, (size_t)(N_NODES + 80) * sizeof(unsigned), stream);
    hist_prep_kernel<<<nb_e + PREP_BLOCKS + WT_BLOCKS, 256, 0, stream>>>(
        ei, DEG, nb_e, x, W0, as0, ad0, XH, ES, ED, W1, W2, WT0, WT1, WT2);
    scan_all_kernel<<<N_SCAN_BLOCKS, SCAN_BS, 0, stream>>>(DEG, RS, BS, DONE, WPTR, N_NODES);
    fill_win_kernel<<<nb_e * FILL_PASSES, 256, 0, stream>>>(ei, WPTR, SRCS);

    const int mfma_blocks = cdiv(N_NODES / 16, 4); // 3125 waves -> 782 blocks

    // ---- layer 0 gather, then fused GEMM0+GEMM1 (layer 1) ----
    aggregate32_kernel<<<NODE_BLOCKS, 256, 0, stream>>>(RS, SRCS, ES, ED, XH, AGG);
    mfma_l01_kernel<<<mfma_blocks, 256, 0, stream>>>(
        AGG, WT0, b0, WT1, as1, ad1, H16, ES, ED, X16A);

    // ---- layer 1 aggregate: residual X16A -> X16B ----
    aggregate96_kernel<<<NODE_BLOCKS, 256, 0, stream>>>(
        RS, SRCS, ES, ED, H16, b1, X16A, X16B, nullptr, nullptr, 1);

    // ---- layer 2: GEMM + aggregate -> HFIN (fused final projection) ----
    mfma_gemm96_kernel<<<mfma_blocks, 256, 0, stream>>>(X16B, WT2, as2, ad2, H16, ES, ED);
    aggregate96_kernel<<<NODE_BLOCKS, 256, 0, stream>>>(
        RS, SRCS, ES, ED, H16, b2, X16B, nullptr, Wf, HFIN, 1);

    // ---- final: HFIN -> out (dout=1) ----
    aggregate1_kernel<<<NODE_BLOCKS, 256, 0, stream>>>(RS, SRCS, HFIN, asf, adf, bf, out);
}

// Round 15
// 353.674 us; speedup vs baseline: 1.0001x; 1.0001x over previous
//
#include <hip/hip_runtime.h>
#include <hip/hip_fp16.h>
#include <math.h>

#define N_NODES 50000
#define N_EDGES 800000
#define E_TOT   (N_EDGES + N_NODES)   // 850000, self-loops appended
#define IN_DIM  32
#define HID     96
#define NEG_SLOPE 0.2f
#define MAXD    128                   // LDS chunk per wave (per-chunk staging)
#define SCAN_BS 1024
#define N_SCAN_BLOCKS ((N_NODES + SCAN_BS - 1) / SCAN_BS)   // 49
#define FILL_PASSES 8
#define FILL_WIN (N_NODES / FILL_PASSES)   // 6250
#define NODE_BLOCKS (N_NODES / 4)          // 12500 blocks of 4 waves/nodes
#define PREP_BLOCKS ((N_NODES * 32) / 256) // 6250
#define WT_BLOCKS (((HID * HID) + 255) / 256) // 36

typedef _Float16 half8v __attribute__((ext_vector_type(8)));
typedef float    float4v __attribute__((ext_vector_type(4)));

static inline int cdiv(long long a, int b) { return (int)((a + b - 1) / b); }

// ---------------- CSR build ----------------
// hist: XCD-pinned windowed passes (pass = blockIdx & 7). Each DEG window receives
// atomics from ONE XCD only -> lines stay in that XCD's L2, no cross-XCD bouncing
// (round-14 counter evidence: single-pass hist wrote 28.8 MB of bounced lines).
__global__ void hist_win_kernel(const int* __restrict__ ei, unsigned* __restrict__ deg) {
    int pass = blockIdx.x & 7;
    int eb   = blockIdx.x >> 3;
    int e = eb * 256 + threadIdx.x;
    if (e >= E_TOT) return;
    int d = (e < N_EDGES) ? ei[N_EDGES + e] : (e - N_EDGES);
    if ((unsigned)(d - pass * FILL_WIN) >= (unsigned)FILL_WIN) return;
    atomicAdd(deg + d, 1u);
}

// full scan in one kernel (49 blocks, internal spin barrier — all co-resident)
__global__ __launch_bounds__(SCAN_BS) void scan_all_kernel(
    const unsigned* __restrict__ deg, unsigned* __restrict__ rs,
    unsigned* __restrict__ bsums, unsigned* __restrict__ done,
    unsigned* __restrict__ wptr, int n) {
    __shared__ unsigned buf[SCAN_BS];
    __shared__ unsigned s_off;
    int i = blockIdx.x * SCAN_BS + threadIdx.x;
    unsigned v = (i < n) ? deg[i] : 0u;
    buf[threadIdx.x] = v;
    __syncthreads();
    for (int o = 1; o < SCAN_BS; o <<= 1) {
        unsigned t = (threadIdx.x >= (unsigned)o) ? buf[threadIdx.x - o] : 0u;
        __syncthreads();
        buf[threadIdx.x] += t;
        __syncthreads();
    }
    unsigned excl = buf[threadIdx.x] - v;
    if (threadIdx.x == SCAN_BS - 1) bsums[blockIdx.x] = buf[SCAN_BS - 1];
    __threadfence();
    __syncthreads();
    if (threadIdx.x == 0) {
        atomicAdd(done, 1u);
        while (atomicAdd(done, 0u) < (unsigned)N_SCAN_BLOCKS) { }
    }
    __syncthreads();
    __threadfence();
    if (threadIdx.x < 64) {
        unsigned pv = ((int)threadIdx.x < (int)blockIdx.x) ? bsums[threadIdx.x] : 0u;
        #pragma unroll
        for (int o = 32; o; o >>= 1) pv += __shfl_xor(pv, o);
        if (threadIdx.x == 0) s_off = pv;
    }
    __syncthreads();
    unsigned off = s_off;
    if (i < n) {
        unsigned r = excl + off;
        rs[i] = r;
        wptr[i] = r;
    }
    if (i == n) rs[n] = E_TOT;
}

// XCD-pinned windowed fill
__global__ void fill_win_kernel(const int* __restrict__ ei, unsigned* __restrict__ wptr,
                                int* __restrict__ srcs) {
    int pass = blockIdx.x & 7;
    int eb   = blockIdx.x >> 3;
    int e = eb * 256 + threadIdx.x;
    if (e >= E_TOT) return;
    int lo = pass * FILL_WIN;
    int d = (e < N_EDGES) ? ei[N_EDGES + e] : (e - N_EDGES);
    if ((unsigned)(d - lo) >= (unsigned)FILL_WIN) return;
    int s = (e < N_EDGES) ? ei[e] : d;
    unsigned pos = atomicAdd(wptr + d, 1u);
    srcs[pos] = s;
}

// ---------------- layer-0 prep (+WT transpose blocks): uproj + scores0 + xcast ----------
__global__ __launch_bounds__(256) void layer0_prep_kernel(
    const float* __restrict__ x, const float* __restrict__ W0,
    const float* __restrict__ as0, const float* __restrict__ ad0,
    __half* __restrict__ xh, float* __restrict__ es, float* __restrict__ ed,
    const float* __restrict__ W1, const float* __restrict__ W2,
    __half* __restrict__ WT0, __half* __restrict__ WT1, __half* __restrict__ WT2) {
    if (blockIdx.x >= PREP_BLOCKS) {
        int i = (blockIdx.x - PREP_BLOCKS) * 256 + threadIdx.x;
        if (i < HID * HID) {
            int n = i / HID, k = i - n * HID;
            WT1[i] = __float2half(W1[k * HID + n]);
            WT2[i] = __float2half(W2[k * HID + n]);
        }
        if (i < HID * IN_DIM) {
            int n = i >> 5, k = i & 31;
            WT0[i] = __float2half(W0[k * HID + n]);
        }
        return;
    }
    __shared__ float s_us[32], s_ud[32];
    if (threadIdx.x < 64) {
        int k = threadIdx.x & 31;
        int sel = threadIdx.x >> 5;
        const float* a = sel ? ad0 : as0;
        float acc = 0.f;
        #pragma unroll 8
        for (int c = 0; c < HID; ++c) acc += W0[k * HID + c] * a[c];
        if (sel) s_ud[k] = acc; else s_us[k] = acc;
    }
    __syncthreads();
    int idx = blockIdx.x * 256 + threadIdx.x;
    int node = idx >> 5;
    int k = threadIdx.x & 31;
    float xv = x[(size_t)node * 32 + k];
    float xnb = __shfl_xor(xv, 1);
    if ((k & 1) == 0) {
        __half2 h2v = __floats2half2_rn(xv, xnb);
        ((__half2*)xh)[((size_t)node * 32 + k) >> 1] = h2v;
    }
    float ps = xv * s_us[k], pd = xv * s_ud[k];
    #pragma unroll
    for (int o = 16; o; o >>= 1) {
        ps += __shfl_xor(ps, o);
        pd += __shfl_xor(pd, o);
    }
    if (k == 0) { es[node] = ps; ed[node] = pd; }
}

// ---------------- layer 0: gather 32-dim fp16 x -> AGG (N*32 fp32) ----------------------
__global__ __launch_bounds__(256) void aggregate32_kernel(
    const unsigned* __restrict__ rs, const int* __restrict__ srcs,
    const float* __restrict__ es, const float* __restrict__ ed,
    const __half* __restrict__ xh, float* __restrict__ agg) {
    __shared__ uint2 sh[4][MAXD];
    int node = (int)((blockIdx.x * (long long)blockDim.x + threadIdx.x) >> 6);
    int lane = threadIdx.x & 63;
    int wv = threadIdx.x >> 6;
    int grp = lane >> 3, lin = lane & 7;
    unsigned row = rs[node];
    int deg = (int)(rs[node + 1] - row);
    float edv = ed[node];

    float lsum = 0.f;
    float4 acc = {0.f, 0.f, 0.f, 0.f};
    const uint2* x2 = (const uint2*)xh;   // row = 8 uint2

    for (int base = 0; base < deg; base += MAXD) {
        int cnt = min(MAXD, deg - base);
        for (int j = lane; j < cnt; j += 64) {
            int s = srcs[row + base + j];
            float v = es[s] + edv;
            v = v > 0.f ? v : NEG_SLOPE * v;
            float e = __expf(v);
            uint2 p; p.x = (unsigned)s; p.y = __float_as_uint(e);
            sh[wv][j] = p;
            lsum += e;
        }
        int jb = 0;
        for (; jb + 16 <= cnt; jb += 16) {
            uint2 pa = sh[wv][jb + grp];
            uint2 pb = sh[wv][jb + 8 + grp];
            uint2 qa = x2[(size_t)pa.x * 8 + lin];
            uint2 qb = x2[(size_t)pb.x * 8 + lin];
            float ea = __uint_as_float(pa.y), eb = __uint_as_float(pb.y);
            float2 fa0 = __half22float2(*(__half2*)&qa.x);
            float2 fa1 = __half22float2(*(__half2*)&qa.y);
            float2 fb0 = __half22float2(*(__half2*)&qb.x);
            float2 fb1 = __half22float2(*(__half2*)&qb.y);
            acc.x += ea * fa0.x + eb * fb0.x; acc.y += ea * fa0.y + eb * fb0.y;
            acc.z += ea * fa1.x + eb * fb1.x; acc.w += ea * fa1.y + eb * fb1.y;
        }
        for (; jb < cnt; jb += 8) {
            int r = jb + grp;
            if (r < cnt) {
                uint2 p = sh[wv][r];
                float e = __uint_as_float(p.y);
                uint2 q = x2[(size_t)p.x * 8 + lin];
                float2 f0 = __half22float2(*(__half2*)&q.x);
                float2 f1 = __half22float2(*(__half2*)&q.y);
                acc.x += e * f0.x; acc.y += e * f0.y;
                acc.z += e * f1.x; acc.w += e * f1.y;
            }
        }
    }
    #pragma unroll
    for (int o = 32; o; o >>= 1) lsum += __shfl_xor(lsum, o);
    #pragma unroll
    for (int o = 8; o <= 32; o <<= 1) {
        acc.x += __shfl_xor(acc.x, o);
        acc.y += __shfl_xor(acc.y, o);
        acc.z += __shfl_xor(acc.z, o);
        acc.w += __shfl_xor(acc.w, o);
    }
    if (grp == 0) {
        float inv = 1.f / lsum;
        float4 o4; o4.x = acc.x * inv; o4.y = acc.y * inv; o4.z = acc.z * inv; o4.w = acc.w * inv;
        ((float4*)agg)[(size_t)node * 8 + lin] = o4;
    }
}

// ---------------- layer 0 GEMM + layer 1 GEMM fused (per-16-node tile, MFMA) ------------
__global__ __launch_bounds__(256) void mfma_l01_kernel(
    const float* __restrict__ agg, const __half* __restrict__ wt0,
    const float* __restrict__ b0, const __half* __restrict__ wt1,
    const float* __restrict__ a_s, const float* __restrict__ a_d,
    __half* __restrict__ h, float* __restrict__ es, float* __restrict__ ed,
    __half* __restrict__ x16a) {
    __shared__ __align__(16) __half tile[4][16 * 96];
    int wid = (int)((blockIdx.x * 256 + threadIdx.x) >> 6);
    if (wid >= N_NODES / 16) return;    // 3125 M-tiles
    int lane = threadIdx.x & 63;
    int wv = threadIdx.x >> 6;
    int col = lane & 15, quad = lane >> 4;
    int m0 = wid * 16;

    half8v a0;
    {
        const float4* ar = (const float4*)(agg + (size_t)(m0 + col) * 32 + quad * 8);
        float4 f0 = ar[0], f1 = ar[1];
        a0[0] = (_Float16)f0.x; a0[1] = (_Float16)f0.y; a0[2] = (_Float16)f0.z; a0[3] = (_Float16)f0.w;
        a0[4] = (_Float16)f1.x; a0[5] = (_Float16)f1.y; a0[6] = (_Float16)f1.z; a0[7] = (_Float16)f1.w;
    }
    #pragma unroll
    for (int t = 0; t < 6; ++t) {
        half8v bfrag = *(const half8v*)(wt0 + (size_t)(t * 16 + col) * 32 + quad * 8);
        float4v c0 = (float4v){0.f, 0.f, 0.f, 0.f};
        c0 = __builtin_amdgcn_mfma_f32_16x16x32_f16(a0, bfrag, c0, 0, 0, 0);
        int n = t * 16 + col;
        float bv = b0[n];
        #pragma unroll
        for (int r = 0; r < 4; ++r) {
            int m = quad * 4 + r;
            float v = fmaxf(c0[r] + bv, 0.f);
            __half hv = __float2half(v);
            tile[wv][m * 96 + n] = hv;
            x16a[(size_t)(m0 + m) * 96 + n] = hv;
        }
    }
    // same-wave LDS RAW — lgkmcnt-ordered

    float4v acc[6];
    #pragma unroll
    for (int t = 0; t < 6; ++t) acc[t] = (float4v){0.f, 0.f, 0.f, 0.f};
    #pragma unroll
    for (int ks = 0; ks < 3; ++ks) {
        half8v afrag = *(const half8v*)(&tile[wv][(lane & 15) * 96 + ks * 32 + quad * 8]);
        #pragma unroll
        for (int t = 0; t < 6; ++t) {
            half8v bfrag = *(const half8v*)(wt1 + (size_t)(t * 16 + col) * 96 + ks * 32 + quad * 8);
            acc[t] = __builtin_amdgcn_mfma_f32_16x16x32_f16(afrag, bfrag, acc[t], 0, 0, 0);
        }
    }

    float ps0 = 0.f, ps1 = 0.f, ps2 = 0.f, ps3 = 0.f;
    float pd0 = 0.f, pd1 = 0.f, pd2 = 0.f, pd3 = 0.f;
    #pragma unroll
    for (int t = 0; t < 6; ++t) {
        int ch = t * 16 + col;
        float sa = a_s[ch], sd = a_d[ch];
        float v0 = acc[t][0], v1 = acc[t][1], v2 = acc[t][2], v3 = acc[t][3];
        size_t rbase = (size_t)(m0 + quad * 4) * 96 + ch;
        h[rbase]       = __float2half(v0);
        h[rbase + 96]  = __float2half(v1);
        h[rbase + 192] = __float2half(v2);
        h[rbase + 288] = __float2half(v3);
        ps0 += v0 * sa; ps1 += v1 * sa; ps2 += v2 * sa; ps3 += v3 * sa;
        pd0 += v0 * sd; pd1 += v1 * sd; pd2 += v2 * sd; pd3 += v3 * sd;
    }
    #pragma unroll
    for (int o = 1; o < 16; o <<= 1) {
        ps0 += __shfl_xor(ps0, o); ps1 += __shfl_xor(ps1, o);
        ps2 += __shfl_xor(ps2, o); ps3 += __shfl_xor(ps3, o);
        pd0 += __shfl_xor(pd0, o); pd1 += __shfl_xor(pd1, o);
        pd2 += __shfl_xor(pd2, o); pd3 += __shfl_xor(pd3, o);
    }
    if (col == 0) {
        int nb = m0 + quad * 4;
        es[nb] = ps0; es[nb + 1] = ps1; es[nb + 2] = ps2; es[nb + 3] = ps3;
        ed[nb] = pd0; ed[nb + 1] = pd1; ed[nb + 2] = pd2; ed[nb + 3] = pd3;
    }
}

// ---------------- layer 2: MFMA GEMM (fp16 in, fp16 h out) with fused scores ------------
__global__ __launch_bounds__(256) void mfma_gemm96_kernel(
    const __half* __restrict__ x16, const __half* __restrict__ wt,
    const float* __restrict__ a_s, const float* __restrict__ a_d,
    __half* __restrict__ h, float* __restrict__ es, float* __restrict__ ed) {
    int wid = (int)((blockIdx.x * 256 + threadIdx.x) >> 6);
    if (wid >= N_NODES / 16) return;
    int lane = threadIdx.x & 63;
    int col = lane & 15, quad = lane >> 4;
    int m0 = wid * 16;
    const __half* arow = x16 + (size_t)(m0 + col) * 96 + quad * 8;
    const __half* brow = wt + (size_t)col * 96 + quad * 8;

    float4v acc[6];
    #pragma unroll
    for (int t = 0; t < 6; ++t) acc[t] = (float4v){0.f, 0.f, 0.f, 0.f};

    #pragma unroll
    for (int ks = 0; ks < 3; ++ks) {
        half8v afrag = *(const half8v*)(arow + ks * 32);
        #pragma unroll
        for (int t = 0; t < 6; ++t) {
            half8v bfrag = *(const half8v*)(brow + (size_t)t * 16 * 96 + ks * 32);
            acc[t] = __builtin_amdgcn_mfma_f32_16x16x32_f16(afrag, bfrag, acc[t], 0, 0, 0);
        }
    }

    float ps0 = 0.f, ps1 = 0.f, ps2 = 0.f, ps3 = 0.f;
    float pd0 = 0.f, pd1 = 0.f, pd2 = 0.f, pd3 = 0.f;
    #pragma unroll
    for (int t = 0; t < 6; ++t) {
        int ch = t * 16 + col;
        float sa = a_s[ch], sd = a_d[ch];
        float v0 = acc[t][0], v1 = acc[t][1], v2 = acc[t][2], v3 = acc[t][3];
        size_t rbase = (size_t)(m0 + quad * 4) * 96 + ch;
        h[rbase]       = __float2half(v0);
        h[rbase + 96]  = __float2half(v1);
        h[rbase + 192] = __float2half(v2);
        h[rbase + 288] = __float2half(v3);
        ps0 += v0 * sa; ps1 += v1 * sa; ps2 += v2 * sa; ps3 += v3 * sa;
        pd0 += v0 * sd; pd1 += v1 * sd; pd2 += v2 * sd; pd3 += v3 * sd;
    }
    #pragma unroll
    for (int o = 1; o < 16; o <<= 1) {
        ps0 += __shfl_xor(ps0, o); ps1 += __shfl_xor(ps1, o);
        ps2 += __shfl_xor(ps2, o); ps3 += __shfl_xor(ps3, o);
        pd0 += __shfl_xor(pd0, o); pd1 += __shfl_xor(pd1, o);
        pd2 += __shfl_xor(pd2, o); pd3 += __shfl_xor(pd3, o);
    }
    if (col == 0) {
        int nb = m0 + quad * 4;
        es[nb] = ps0; es[nb + 1] = ps1; es[nb + 2] = ps2; es[nb + 3] = ps3;
        ed[nb] = pd0; ed[nb + 1] = pd1; ed[nb + 2] = pd2; ed[nb + 3] = pd3;
    }
}

// ---------------- fused softmax + gather (96ch), 16/8/2-row pipeline ---------------------
__global__ __launch_bounds__(256) void aggregate96_kernel(
    const unsigned* __restrict__ rs, const int* __restrict__ srcs,
    const float* __restrict__ es, const float* __restrict__ ed,
    const __half* __restrict__ h, const float* __restrict__ b,
    const __half* __restrict__ res16, __half* __restrict__ out16,
    const float* __restrict__ Wf, float* __restrict__ hfin, int do_relu) {
    __shared__ uint2 sh[4][MAXD];
    int node = (int)((blockIdx.x * (long long)blockDim.x + threadIdx.x) >> 6);
    int lane = threadIdx.x & 63;
    int wv = threadIdx.x >> 6;
    int half_ = lane >> 5, lin = lane & 31;
    unsigned row = rs[node];
    int deg = (int)(rs[node + 1] - row);
    float edv = ed[node];

    float lsum = 0.f;
    float4 acc = {0.f, 0.f, 0.f, 0.f};
    const uint2* h4 = (const uint2*)h;
    bool act = (lin < 24);

    for (int base = 0; base < deg; base += MAXD) {
        int cnt = min(MAXD, deg - base);
        for (int j = lane; j < cnt; j += 64) {
            int s = srcs[row + base + j];
            float v = es[s] + edv;
            v = v > 0.f ? v : NEG_SLOPE * v;
            float e = __expf(v);
            uint2 p; p.x = (unsigned)s; p.y = __float_as_uint(e);
            sh[wv][j] = p;
            lsum += e;
        }
        int jb = 0;
        for (; jb + 16 <= cnt; jb += 16) {
            uint2 pp[8];
            #pragma unroll
            for (int u = 0; u < 8; ++u) pp[u] = sh[wv][jb + 2 * u + half_];
            if (act) {
                uint2 qq[8];
                #pragma unroll
                for (int u = 0; u < 8; ++u) qq[u] = h4[(size_t)pp[u].x * 24 + lin];
                #pragma unroll
                for (int u = 0; u < 8; ++u) {
                    float e = __uint_as_float(pp[u].y);
                    float2 f0 = __half22float2(*(__half2*)&qq[u].x);
                    float2 f1 = __half22float2(*(__half2*)&qq[u].y);
                    acc.x += e * f0.x; acc.y += e * f0.y;
                    acc.z += e * f1.x; acc.w += e * f1.y;
                }
            }
        }
        for (; jb + 8 <= cnt; jb += 8) {
            uint2 pp[4];
            #pragma unroll
            for (int u = 0; u < 4; ++u) pp[u] = sh[wv][jb + 2 * u + half_];
            if (act) {
                uint2 qq[4];
                #pragma unroll
                for (int u = 0; u < 4; ++u) qq[u] = h4[(size_t)pp[u].x * 24 + lin];
                #pragma unroll
                for (int u = 0; u < 4; ++u) {
                    float e = __uint_as_float(pp[u].y);
                    float2 f0 = __half22float2(*(__half2*)&qq[u].x);
                    float2 f1 = __half22float2(*(__half2*)&qq[u].y);
                    acc.x += e * f0.x; acc.y += e * f0.y;
                    acc.z += e * f1.x; acc.w += e * f1.y;
                }
            }
        }
        for (; jb < cnt; jb += 2) {
            int r = jb + half_;
            if (act && r < cnt) {
                uint2 p = sh[wv][r];
                float e = __uint_as_float(p.y);
                uint2 q = h4[(size_t)p.x * 24 + lin];
                float2 f0 = __half22float2(*(__half2*)&q.x);
                float2 f1 = __half22float2(*(__half2*)&q.y);
                acc.x += e * f0.x; acc.y += e * f0.y;
                acc.z += e * f1.x; acc.w += e * f1.y;
            }
        }
    }
    #pragma unroll
    for (int o = 32; o; o >>= 1) lsum += __shfl_xor(lsum, o);
    acc.x += __shfl_xor(acc.x, 32);
    acc.y += __shfl_xor(acc.y, 32);
    acc.z += __shfl_xor(acc.z, 32);
    acc.w += __shfl_xor(acc.w, 32);

    float pfin = 0.f;
    if (half_ == 0 && lin < 24) {
        float inv = 1.f / lsum;
        float4 bb = ((const float4*)b)[lin];
        float4 v;
        v.x = acc.x * inv + bb.x; v.y = acc.y * inv + bb.y;
        v.z = acc.z * inv + bb.z; v.w = acc.w * inv + bb.w;
        if (res16) {
            uint2 rr = ((const uint2*)res16)[(size_t)node * 24 + lin];
            float2 r0 = __half22float2(*(__half2*)&rr.x);
            float2 r1 = __half22float2(*(__half2*)&rr.y);
            v.x += r0.x; v.y += r0.y; v.z += r1.x; v.w += r1.y;
        }
        if (do_relu) {
            v.x = fmaxf(v.x, 0.f); v.y = fmaxf(v.y, 0.f);
            v.z = fmaxf(v.z, 0.f); v.w = fmaxf(v.w, 0.f);
        }
        if (out16) {
            __half2 q0 = __floats2half2_rn(v.x, v.y), q1 = __floats2half2_rn(v.z, v.w);
            uint2 st; st.x = *(unsigned*)&q0; st.y = *(unsigned*)&q1;
            ((uint2*)out16)[(size_t)node * 24 + lin] = st;
        }
        if (hfin) {
            float4 wf = ((const float4*)Wf)[lin];
            pfin = v.x * wf.x + v.y * wf.y + v.z * wf.z + v.w * wf.w;
        }
    }
    if (hfin) {
        #pragma unroll
        for (int o = 1; o < 32; o <<= 1) pfin += __shfl_xor(pfin, o);
        if (lane == 0) hfin[node] = pfin;
    }
}

// ---------------- final dout=1 aggregate ----------------
__global__ __launch_bounds__(256) void aggregate1_kernel(
    const unsigned* __restrict__ rs, const int* __restrict__ srcs,
    const float* __restrict__ hfin, const float* __restrict__ asf,
    const float* __restrict__ adf, const float* __restrict__ bf,
    float* __restrict__ out) {
    int node = (int)((blockIdx.x * (long long)blockDim.x + threadIdx.x) >> 6);
    int lane = threadIdx.x & 63;
    unsigned row = rs[node];
    int deg = (int)(rs[node + 1] - row);
    float as0 = asf[0], ad0 = adf[0];
    float edv = hfin[node] * ad0;

    float lsum = 0.f, acc = 0.f;
    for (int j = lane; j < deg; j += 64) {
        int s = srcs[row + j];
        float hs = hfin[s];
        float v = as0 * hs + edv;
        v = v > 0.f ? v : NEG_SLOPE * v;
        float ex = __expf(v);
        lsum += ex;
        acc += ex * hs;
    }
    #pragma unroll
    for (int o = 32; o; o >>= 1) {
        lsum += __shfl_xor(lsum, o);
        acc  += __shfl_xor(acc, o);
    }
    if (lane == 0) out[node] = acc / lsum + bf[0];
}

// ---------------- host-side orchestration ----------------

extern "C" void kernel_launch(void* const* d_in, const int* in_sizes, int n_in,
                              void* d_out, int out_size, void* d_ws, size_t ws_size,
                              hipStream_t stream) {
    const float* x  = (const float*)d_in[0];
    const int*   ei = (const int*)d_in[1];
    const float* W0 = (const float*)d_in[3];
    const float* as0 = (const float*)d_in[4];
    const float* ad0 = (const float*)d_in[5];
    const float* b0 = (const float*)d_in[6];
    const float* W1 = (const float*)d_in[7];
    const float* as1 = (const float*)d_in[8];
    const float* ad1 = (const float*)d_in[9];
    const float* b1 = (const float*)d_in[10];
    const float* W2 = (const float*)d_in[11];
    const float* as2 = (const float*)d_in[12];
    const float* ad2 = (const float*)d_in[13];
    const float* b2 = (const float*)d_in[14];
    const float* Wf = (const float*)d_in[15];
    const float* asf = (const float*)d_in[16];
    const float* adf = (const float*)d_in[17];
    const float* bf = (const float*)d_in[18];

    float* out = (float*)d_out;  // 50000 floats

    // workspace carve-up
    float* Hf = (float*)d_ws;                    // N*96 float slot: DEG/BS/DONE early, H16 later
    __half* H16 = (__half*)Hf;
    float* ES = Hf + (long long)N_NODES * HID;   // N
    float* ED = ES + N_NODES;                    // N
    unsigned* RS   = (unsigned*)(ED + N_NODES);  // N+1
    unsigned* WPTR = RS + (N_NODES + 1);         // N
    int* SRCS = (int*)(WPTR + N_NODES);          // E_TOT
    __half* XH  = (__half*)(SRCS + E_TOT + 2);   // N*32 halves (dedicated)
    __half* X16A = XH + (size_t)N_NODES * IN_DIM;  // N*96 halves
    __half* X16B = X16A + (size_t)N_NODES * HID;   // N*96 halves
    __half* WT0 = X16B + (size_t)N_NODES * HID;    // 96*32 halves
    __half* WT1 = WT0 + HID * IN_DIM;              // 96*96 halves
    __half* WT2 = WT1 + HID * HID;                 // 96*96 halves
    float* HFIN = (float*)(WT2 + HID * HID);       // N floats
    float* AGG  = HFIN + N_NODES;                  // N*32 fp32
    unsigned* DEG = (unsigned*)Hf;               // CSR temps aliased onto Hf (pre-MFMA)
    unsigned* BS  = DEG + N_NODES;               // 49
    unsigned* DONE = BS + 64;                    // 1

    const int nb_e = cdiv(E_TOT, 256);

    // ---- CSR build + layer-0 prep ----
    hipMemsetAsync(DEG, 0, (size_t)(N_NODES + 80) * sizeof(unsigned), stream);
    hist_win_kernel<<<nb_e * FILL_PASSES, 256, 0, stream>>>(ei, DEG);
    layer0_prep_kernel<<<PREP_BLOCKS + WT_BLOCKS, 256, 0, stream>>>(
        x, W0, as0, ad0, XH, ES, ED, W1, W2, WT0, WT1, WT2);
    scan_all_kernel<<<N_SCAN_BLOCKS, SCAN_BS, 0, stream>>>(DEG, RS, BS, DONE, WPTR, N_NODES);
    fill_win_kernel<<<nb_e * FILL_PASSES, 256, 0, stream>>>(ei, WPTR, SRCS);

    const int mfma_blocks = cdiv(N_NODES / 16, 4); // 3125 waves -> 782 blocks

    // ---- layer 0 gather, then fused GEMM0+GEMM1 (layer 1) ----
    aggregate32_kernel<<<NODE_BLOCKS, 256, 0, stream>>>(RS, SRCS, ES, ED, XH, AGG);
    mfma_l01_kernel<<<mfma_blocks, 256, 0, stream>>>(
        AGG, WT0, b0, WT1, as1, ad1, H16, ES, ED, X16A);

    // ---- layer 1 aggregate: residual X16A -> X16B ----
    aggregate96_kernel<<<NODE_BLOCKS, 256, 0, stream>>>(
        RS, SRCS, ES, ED, H16, b1, X16A, X16B, nullptr, nullptr, 1);

    // ---- layer 2: GEMM + aggregate -> HFIN (fused final projection) ----
    mfma_gemm96_kernel<<<mfma_blocks, 256, 0, stream>>>(X16B, WT2, as2, ad2, H16, ES, ED);
    aggregate96_kernel<<<NODE_BLOCKS, 256, 0, stream>>>(
        RS, SRCS, ES, ED, H16, b2, X16B, nullptr, Wf, HFIN, 1);

    // ---- final: HFIN -> out (dout=1) ----
    aggregate1_kernel<<<NODE_BLOCKS, 256, 0, stream>>>(RS, SRCS, HFIN, asf, adf, bf, out);
}

// Round 16
// 337.822 us; speedup vs baseline: 1.0471x; 1.0469x over previous
//
#include <hip/hip_runtime.h>
#include <hip/hip_fp16.h>
#include <math.h>

#define N_NODES 50000
#define N_EDGES 800000
#define E_TOT   (N_EDGES + N_NODES)   // 850000, self-loops appended
#define IN_DIM  32
#define HID     96
#define NEG_SLOPE 0.2f
#define MAXD    128                   // LDS chunk per wave (per-chunk staging)
#define SCAN_BS 1024
#define N_SCAN_BLOCKS ((N_NODES + SCAN_BS - 1) / SCAN_BS)   // 49
#define FILL_PASSES 8
#define FILL_WIN (N_NODES / FILL_PASSES)   // 6250
#define NODE_BLOCKS (N_NODES / 4)          // 12500 blocks of 4 waves/nodes
#define PREP_BLOCKS ((N_NODES * 32) / 256) // 6250
#define WT_BLOCKS (((HID * HID) + 255) / 256) // 36

typedef _Float16 half8v __attribute__((ext_vector_type(8)));
typedef float    float4v __attribute__((ext_vector_type(4)));

static inline int cdiv(long long a, int b) { return (int)((a + b - 1) / b); }

// ---------------- CSR build (round-13 structure: best measured) ----------------

__global__ void hist_kernel(const int* __restrict__ ei, unsigned* __restrict__ deg) {
    int e = blockIdx.x * blockDim.x + threadIdx.x;
    if (e >= E_TOT) return;
    int d = (e < N_EDGES) ? ei[N_EDGES + e] : (e - N_EDGES);
    atomicAdd(deg + d, 1u);
}

__global__ void scan_block_kernel(const unsigned* __restrict__ deg, unsigned* __restrict__ rs,
                                  unsigned* __restrict__ bsums, int n) {
    __shared__ unsigned buf[SCAN_BS];
    int i = blockIdx.x * SCAN_BS + threadIdx.x;
    unsigned v = (i < n) ? deg[i] : 0u;
    buf[threadIdx.x] = v;
    __syncthreads();
    for (int o = 1; o < SCAN_BS; o <<= 1) {
        unsigned t = (threadIdx.x >= (unsigned)o) ? buf[threadIdx.x - o] : 0u;
        __syncthreads();
        buf[threadIdx.x] += t;
        __syncthreads();
    }
    if (i < n) rs[i] = buf[threadIdx.x] - v;
    if (threadIdx.x == SCAN_BS - 1) bsums[blockIdx.x] = buf[SCAN_BS - 1];
}

__global__ void scan_fix_kernel(unsigned* __restrict__ rs, const unsigned* __restrict__ bsums,
                                unsigned* __restrict__ wptr, int n) {
    __shared__ unsigned s_off;
    int k = blockIdx.x >> 2;
    if (threadIdx.x < 64) {
        unsigned v = ((int)threadIdx.x < k) ? bsums[threadIdx.x] : 0u;
        #pragma unroll
        for (int o = 32; o; o >>= 1) v += __shfl_xor(v, o);
        if (threadIdx.x == 0) s_off = v;
    }
    __syncthreads();
    unsigned off = s_off;
    int i = blockIdx.x * 256 + threadIdx.x;
    if (i < n) {
        unsigned r = rs[i] + off;
        rs[i] = r;
        wptr[i] = r;
    }
    if (i == n) rs[n] = E_TOT;
}

__global__ void fill_win_kernel(const int* __restrict__ ei, unsigned* __restrict__ wptr,
                                int* __restrict__ srcs) {
    int pass = blockIdx.x & 7;          // XCD-pinned pass
    int eb   = blockIdx.x >> 3;
    int e = eb * 256 + threadIdx.x;
    if (e >= E_TOT) return;
    int lo = pass * FILL_WIN;
    int d = (e < N_EDGES) ? ei[N_EDGES + e] : (e - N_EDGES);
    if ((unsigned)(d - lo) >= (unsigned)FILL_WIN) return;
    int s = (e < N_EDGES) ? ei[e] : d;
    unsigned pos = atomicAdd(wptr + d, 1u);
    srcs[pos] = s;
}

// ---------------- layer-0 prep (+WT transpose blocks): uproj + scores0 + xcast ----------
__global__ __launch_bounds__(256) void layer0_prep_kernel(
    const float* __restrict__ x, const float* __restrict__ W0,
    const float* __restrict__ as0, const float* __restrict__ ad0,
    __half* __restrict__ xh, float* __restrict__ es, float* __restrict__ ed,
    const float* __restrict__ W1, const float* __restrict__ W2,
    __half* __restrict__ WT1, __half* __restrict__ WT2) {
    if (blockIdx.x >= PREP_BLOCKS) {
        int i = (blockIdx.x - PREP_BLOCKS) * 256 + threadIdx.x;
        if (i < HID * HID) {
            int n = i / HID, k = i - n * HID;
            WT1[i] = __float2half(W1[k * HID + n]);
            WT2[i] = __float2half(W2[k * HID + n]);
        }
        return;
    }
    __shared__ float s_us[32], s_ud[32];
    if (threadIdx.x < 64) {
        int k = threadIdx.x & 31;
        int sel = threadIdx.x >> 5;
        const float* a = sel ? ad0 : as0;
        float acc = 0.f;
        #pragma unroll 8
        for (int c = 0; c < HID; ++c) acc += W0[k * HID + c] * a[c];
        if (sel) s_ud[k] = acc; else s_us[k] = acc;
    }
    __syncthreads();
    int idx = blockIdx.x * 256 + threadIdx.x;
    int node = idx >> 5;
    int k = threadIdx.x & 31;
    float xv = x[(size_t)node * 32 + k];
    float xnb = __shfl_xor(xv, 1);
    if ((k & 1) == 0) {
        __half2 h2v = __floats2half2_rn(xv, xnb);
        ((__half2*)xh)[((size_t)node * 32 + k) >> 1] = h2v;
    }
    float ps = xv * s_us[k], pd = xv * s_ud[k];
    #pragma unroll
    for (int o = 16; o; o >>= 1) {
        ps += __shfl_xor(ps, o);
        pd += __shfl_xor(pd, o);
    }
    if (k == 0) { es[node] = ps; ed[node] = pd; }
}

// ---------------- layer 0: gather 32-dim fp16 x -> AGG (N*32 fp32) ----------------------
__global__ __launch_bounds__(256) void aggregate32_kernel(
    const unsigned* __restrict__ rs, const int* __restrict__ srcs,
    const float* __restrict__ es, const float* __restrict__ ed,
    const __half* __restrict__ xh, float* __restrict__ agg) {
    __shared__ uint2 sh[4][MAXD];
    int node = (int)((blockIdx.x * (long long)blockDim.x + threadIdx.x) >> 6);
    int lane = threadIdx.x & 63;
    int wv = threadIdx.x >> 6;
    int grp = lane >> 3, lin = lane & 7;
    unsigned row = rs[node];
    int deg = (int)(rs[node + 1] - row);
    float edv = ed[node];

    float lsum = 0.f;
    float4 acc = {0.f, 0.f, 0.f, 0.f};
    const uint2* x2 = (const uint2*)xh;   // row = 8 uint2

    for (int base = 0; base < deg; base += MAXD) {
        int cnt = min(MAXD, deg - base);
        for (int j = lane; j < cnt; j += 64) {
            int s = srcs[row + base + j];
            float v = es[s] + edv;
            v = v > 0.f ? v : NEG_SLOPE * v;
            float e = __expf(v);
            uint2 p; p.x = (unsigned)s; p.y = __float_as_uint(e);
            sh[wv][j] = p;
            lsum += e;
        }
        int jb = 0;
        for (; jb + 16 <= cnt; jb += 16) {
            uint2 pa = sh[wv][jb + grp];
            uint2 pb = sh[wv][jb + 8 + grp];
            uint2 qa = x2[(size_t)pa.x * 8 + lin];
            uint2 qb = x2[(size_t)pb.x * 8 + lin];
            float ea = __uint_as_float(pa.y), eb = __uint_as_float(pb.y);
            float2 fa0 = __half22float2(*(__half2*)&qa.x);
            float2 fa1 = __half22float2(*(__half2*)&qa.y);
            float2 fb0 = __half22float2(*(__half2*)&qb.x);
            float2 fb1 = __half22float2(*(__half2*)&qb.y);
            acc.x += ea * fa0.x + eb * fb0.x; acc.y += ea * fa0.y + eb * fb0.y;
            acc.z += ea * fa1.x + eb * fb1.x; acc.w += ea * fa1.y + eb * fb1.y;
        }
        for (; jb < cnt; jb += 8) {
            int r = jb + grp;
            if (r < cnt) {
                uint2 p = sh[wv][r];
                float e = __uint_as_float(p.y);
                uint2 q = x2[(size_t)p.x * 8 + lin];
                float2 f0 = __half22float2(*(__half2*)&q.x);
                float2 f1 = __half22float2(*(__half2*)&q.y);
                acc.x += e * f0.x; acc.y += e * f0.y;
                acc.z += e * f1.x; acc.w += e * f1.y;
            }
        }
    }
    #pragma unroll
    for (int o = 32; o; o >>= 1) lsum += __shfl_xor(lsum, o);
    #pragma unroll
    for (int o = 8; o <= 32; o <<= 1) {
        acc.x += __shfl_xor(acc.x, o);
        acc.y += __shfl_xor(acc.y, o);
        acc.z += __shfl_xor(acc.z, o);
        acc.w += __shfl_xor(acc.w, o);
    }
    if (grp == 0) {
        float inv = 1.f / lsum;
        float4 o4; o4.x = acc.x * inv; o4.y = acc.y * inv; o4.z = acc.z * inv; o4.w = acc.w * inv;
        ((float4*)agg)[(size_t)node * 8 + lin] = o4;
    }
}

// relu(agg @ W0 + b0) -> X16A fp16 (4-node x 4-ch micro-tile, W0 reuse)
__global__ void gemm32_kernel(const float* __restrict__ agg, const float* __restrict__ W,
                              const float* __restrict__ b, __half* __restrict__ out16) {
    int idx = blockIdx.x * blockDim.x + threadIdx.x;   // (n/4)*24 threads
    if (idx >= (N_NODES / 4) * 24) return;
    int g   = idx / 24;
    int c4q = idx - g * 24;
    int n0 = g * 4;
    const float4* Xa = (const float4*)agg + (size_t)n0 * 8;
    const float4* Xb = Xa + 8;
    const float4* Xc = Xb + 8;
    const float4* Xd = Xc + 8;
    const float4* W4 = (const float4*)W;   // row stride 24 float4

    float4 accA = {0,0,0,0}, accB = {0,0,0,0}, accC = {0,0,0,0}, accD = {0,0,0,0};
    for (int k4 = 0; k4 < 8; ++k4) {
        float4 xa = Xa[k4], xb = Xb[k4], xc = Xc[k4], xd = Xd[k4];
        #pragma unroll
        for (int kk = 0; kk < 4; ++kk) {
            float4 w = W4[(size_t)(k4 * 4 + kk) * 24 + c4q];
            float sa = ((const float*)&xa)[kk], sb = ((const float*)&xb)[kk];
            float sc = ((const float*)&xc)[kk], sd = ((const float*)&xd)[kk];
            accA.x += sa * w.x; accA.y += sa * w.y; accA.z += sa * w.z; accA.w += sa * w.w;
            accB.x += sb * w.x; accB.y += sb * w.y; accB.z += sb * w.z; accB.w += sb * w.w;
            accC.x += sc * w.x; accC.y += sc * w.y; accC.z += sc * w.z; accC.w += sc * w.w;
            accD.x += sd * w.x; accD.y += sd * w.y; accD.z += sd * w.z; accD.w += sd * w.w;
        }
    }
    float4 bb = ((const float4*)b)[c4q];
    uint2* O16 = (uint2*)out16;
    #pragma unroll
    for (int nn = 0; nn < 4; ++nn) {
        float4 a = (nn == 0) ? accA : (nn == 1) ? accB : (nn == 2) ? accC : accD;
        float rx = fmaxf(a.x + bb.x, 0.f), ry = fmaxf(a.y + bb.y, 0.f);
        float rz = fmaxf(a.z + bb.z, 0.f), rw = fmaxf(a.w + bb.w, 0.f);
        __half2 q0 = __floats2half2_rn(rx, ry), q1 = __floats2half2_rn(rz, rw);
        uint2 st; st.x = *(unsigned*)&q0; st.y = *(unsigned*)&q1;
        O16[(size_t)(n0 + nn) * 24 + c4q] = st;
    }
}

// ---------------- layers 1,2: MFMA GEMM (fp16 in, fp16 h out) with fused scores ---------
__global__ __launch_bounds__(256) void mfma_gemm96_kernel(
    const __half* __restrict__ x16, const __half* __restrict__ wt,
    const float* __restrict__ a_s, const float* __restrict__ a_d,
    __half* __restrict__ h, float* __restrict__ es, float* __restrict__ ed) {
    int wid = (int)((blockIdx.x * 256 + threadIdx.x) >> 6);
    if (wid >= N_NODES / 16) return;
    int lane = threadIdx.x & 63;
    int col = lane & 15, quad = lane >> 4;
    int m0 = wid * 16;
    const __half* arow = x16 + (size_t)(m0 + col) * 96 + quad * 8;
    const __half* brow = wt + (size_t)col * 96 + quad * 8;

    float4v acc[6];
    #pragma unroll
    for (int t = 0; t < 6; ++t) acc[t] = (float4v){0.f, 0.f, 0.f, 0.f};

    #pragma unroll
    for (int ks = 0; ks < 3; ++ks) {
        half8v afrag = *(const half8v*)(arow + ks * 32);
        #pragma unroll
        for (int t = 0; t < 6; ++t) {
            half8v bfrag = *(const half8v*)(brow + (size_t)t * 16 * 96 + ks * 32);
            acc[t] = __builtin_amdgcn_mfma_f32_16x16x32_f16(afrag, bfrag, acc[t], 0, 0, 0);
        }
    }

    float ps0 = 0.f, ps1 = 0.f, ps2 = 0.f, ps3 = 0.f;
    float pd0 = 0.f, pd1 = 0.f, pd2 = 0.f, pd3 = 0.f;
    #pragma unroll
    for (int t = 0; t < 6; ++t) {
        int ch = t * 16 + col;
        float sa = a_s[ch], sd = a_d[ch];
        float v0 = acc[t][0], v1 = acc[t][1], v2 = acc[t][2], v3 = acc[t][3];
        size_t rbase = (size_t)(m0 + quad * 4) * 96 + ch;
        h[rbase]       = __float2half(v0);
        h[rbase + 96]  = __float2half(v1);
        h[rbase + 192] = __float2half(v2);
        h[rbase + 288] = __float2half(v3);
        ps0 += v0 * sa; ps1 += v1 * sa; ps2 += v2 * sa; ps3 += v3 * sa;
        pd0 += v0 * sd; pd1 += v1 * sd; pd2 += v2 * sd; pd3 += v3 * sd;
    }
    #pragma unroll
    for (int o = 1; o < 16; o <<= 1) {
        ps0 += __shfl_xor(ps0, o); ps1 += __shfl_xor(ps1, o);
        ps2 += __shfl_xor(ps2, o); ps3 += __shfl_xor(ps3, o);
        pd0 += __shfl_xor(pd0, o); pd1 += __shfl_xor(pd1, o);
        pd2 += __shfl_xor(pd2, o); pd3 += __shfl_xor(pd3, o);
    }
    if (col == 0) {
        int nb = m0 + quad * 4;
        es[nb] = ps0; es[nb + 1] = ps1; es[nb + 2] = ps2; es[nb + 3] = ps3;
        ed[nb] = pd0; ed[nb + 1] = pd1; ed[nb + 2] = pd2; ed[nb + 3] = pd3;
    }
}

// ---------------- fused softmax + gather (96ch): uint4 loads, 4 rows/instruction --------
// Row = 12 uint4 (96 halves). Lane groups of 16 (grp4 = lane>>4) each take one row;
// lanes lin<12 active -> 4 rows per load instruction, x2 unroll = 8 rows in flight.
__global__ __launch_bounds__(256) void aggregate96_kernel(
    const unsigned* __restrict__ rs, const int* __restrict__ srcs,
    const float* __restrict__ es, const float* __restrict__ ed,
    const __half* __restrict__ h, const float* __restrict__ b,
    const __half* __restrict__ res16, __half* __restrict__ out16,
    const float* __restrict__ Wf, float* __restrict__ hfin, int do_relu) {
    __shared__ uint2 sh[4][MAXD];
    int node = (int)((blockIdx.x * (long long)blockDim.x + threadIdx.x) >> 6);
    int lane = threadIdx.x & 63;
    int wv = threadIdx.x >> 6;
    int grp4 = lane >> 4, lin = lane & 15;
    unsigned row = rs[node];
    int deg = (int)(rs[node + 1] - row);
    float edv = ed[node];

    float lsum = 0.f;
    float a0 = 0.f, a1 = 0.f, a2 = 0.f, a3 = 0.f, a4 = 0.f, a5 = 0.f, a6 = 0.f, a7 = 0.f;
    const uint4* h8 = (const uint4*)h;    // row = 12 uint4
    bool act = (lin < 12);

    for (int base = 0; base < deg; base += MAXD) {
        int cnt = min(MAXD, deg - base);
        for (int j = lane; j < cnt; j += 64) {
            int s = srcs[row + base + j];
            float v = es[s] + edv;
            v = v > 0.f ? v : NEG_SLOPE * v;
            float e = __expf(v);
            uint2 p; p.x = (unsigned)s; p.y = __float_as_uint(e);
            sh[wv][j] = p;   // same-wave RAW, ordered by lgkmcnt
            lsum += e;
        }
        int jb = 0;
        for (; jb + 8 <= cnt; jb += 8) {
            uint2 pa = sh[wv][jb + grp4];
            uint2 pb = sh[wv][jb + 4 + grp4];
            if (act) {
                uint4 qa = h8[(size_t)pa.x * 12 + lin];
                uint4 qb = h8[(size_t)pb.x * 12 + lin];
                float ea = __uint_as_float(pa.y), eb = __uint_as_float(pb.y);
                float2 fa0 = __half22float2(*(__half2*)&qa.x);
                float2 fa1 = __half22float2(*(__half2*)&qa.y);
                float2 fa2 = __half22float2(*(__half2*)&qa.z);
                float2 fa3 = __half22float2(*(__half2*)&qa.w);
                float2 fb0 = __half22float2(*(__half2*)&qb.x);
                float2 fb1 = __half22float2(*(__half2*)&qb.y);
                float2 fb2 = __half22float2(*(__half2*)&qb.z);
                float2 fb3 = __half22float2(*(__half2*)&qb.w);
                a0 += ea * fa0.x + eb * fb0.x; a1 += ea * fa0.y + eb * fb0.y;
                a2 += ea * fa1.x + eb * fb1.x; a3 += ea * fa1.y + eb * fb1.y;
                a4 += ea * fa2.x + eb * fb2.x; a5 += ea * fa2.y + eb * fb2.y;
                a6 += ea * fa3.x + eb * fb3.x; a7 += ea * fa3.y + eb * fb3.y;
            }
        }
        for (; jb < cnt; jb += 4) {
            int r = jb + grp4;
            if (act && r < cnt) {
                uint2 p = sh[wv][r];
                float e = __uint_as_float(p.y);
                uint4 q = h8[(size_t)p.x * 12 + lin];
                float2 f0 = __half22float2(*(__half2*)&q.x);
                float2 f1 = __half22float2(*(__half2*)&q.y);
                float2 f2 = __half22float2(*(__half2*)&q.z);
                float2 f3 = __half22float2(*(__half2*)&q.w);
                a0 += e * f0.x; a1 += e * f0.y;
                a2 += e * f1.x; a3 += e * f1.y;
                a4 += e * f2.x; a5 += e * f2.y;
                a6 += e * f3.x; a7 += e * f3.y;
            }
        }
    }
    #pragma unroll
    for (int o = 32; o; o >>= 1) lsum += __shfl_xor(lsum, o);
    a0 += __shfl_xor(a0, 16); a0 += __shfl_xor(a0, 32);
    a1 += __shfl_xor(a1, 16); a1 += __shfl_xor(a1, 32);
    a2 += __shfl_xor(a2, 16); a2 += __shfl_xor(a2, 32);
    a3 += __shfl_xor(a3, 16); a3 += __shfl_xor(a3, 32);
    a4 += __shfl_xor(a4, 16); a4 += __shfl_xor(a4, 32);
    a5 += __shfl_xor(a5, 16); a5 += __shfl_xor(a5, 32);
    a6 += __shfl_xor(a6, 16); a6 += __shfl_xor(a6, 32);
    a7 += __shfl_xor(a7, 16); a7 += __shfl_xor(a7, 32);

    float pfin = 0.f;
    if (lane < 12) {   // grp4==0 && lin<12: owns channels [lane*8, lane*8+8)
        float inv = 1.f / lsum;
        const float4* b4 = (const float4*)b;
        float4 bb0 = b4[lane * 2], bb1 = b4[lane * 2 + 1];
        float v0 = a0 * inv + bb0.x, v1 = a1 * inv + bb0.y;
        float v2 = a2 * inv + bb0.z, v3 = a3 * inv + bb0.w;
        float v4 = a4 * inv + bb1.x, v5 = a5 * inv + bb1.y;
        float v6 = a6 * inv + bb1.z, v7 = a7 * inv + bb1.w;
        if (res16) {
            uint4 rr = ((const uint4*)res16)[(size_t)node * 12 + lane];
            float2 r0 = __half22float2(*(__half2*)&rr.x);
            float2 r1 = __half22float2(*(__half2*)&rr.y);
            float2 r2 = __half22float2(*(__half2*)&rr.z);
            float2 r3 = __half22float2(*(__half2*)&rr.w);
            v0 += r0.x; v1 += r0.y; v2 += r1.x; v3 += r1.y;
            v4 += r2.x; v5 += r2.y; v6 += r3.x; v7 += r3.y;
        }
        if (do_relu) {
            v0 = fmaxf(v0, 0.f); v1 = fmaxf(v1, 0.f); v2 = fmaxf(v2, 0.f); v3 = fmaxf(v3, 0.f);
            v4 = fmaxf(v4, 0.f); v5 = fmaxf(v5, 0.f); v6 = fmaxf(v6, 0.f); v7 = fmaxf(v7, 0.f);
        }
        if (out16) {
            __half2 q0 = __floats2half2_rn(v0, v1), q1 = __floats2half2_rn(v2, v3);
            __half2 q2 = __floats2half2_rn(v4, v5), q3 = __floats2half2_rn(v6, v7);
            uint4 st; st.x = *(unsigned*)&q0; st.y = *(unsigned*)&q1;
            st.z = *(unsigned*)&q2; st.w = *(unsigned*)&q3;
            ((uint4*)out16)[(size_t)node * 12 + lane] = st;
        }
        if (hfin) {
            const float4* w4 = (const float4*)Wf;
            float4 wf0 = w4[lane * 2], wf1 = w4[lane * 2 + 1];
            pfin = v0 * wf0.x + v1 * wf0.y + v2 * wf0.z + v3 * wf0.w
                 + v4 * wf1.x + v5 * wf1.y + v6 * wf1.z + v7 * wf1.w;
        }
    }
    if (hfin) {
        #pragma unroll
        for (int o = 1; o < 16; o <<= 1) pfin += __shfl_xor(pfin, o);
        if (lane == 0) hfin[node] = pfin;
    }
}

// ---------------- final dout=1 aggregate ----------------
__global__ __launch_bounds__(256) void aggregate1_kernel(
    const unsigned* __restrict__ rs, const int* __restrict__ srcs,
    const float* __restrict__ hfin, const float* __restrict__ asf,
    const float* __restrict__ adf, const float* __restrict__ bf,
    float* __restrict__ out) {
    int node = (int)((blockIdx.x * (long long)blockDim.x + threadIdx.x) >> 6);
    int lane = threadIdx.x & 63;
    unsigned row = rs[node];
    int deg = (int)(rs[node + 1] - row);
    float as0 = asf[0], ad0 = adf[0];
    float edv = hfin[node] * ad0;

    float lsum = 0.f, acc = 0.f;
    for (int j = lane; j < deg; j += 64) {
        int s = srcs[row + j];
        float hs = hfin[s];
        float v = as0 * hs + edv;
        v = v > 0.f ? v : NEG_SLOPE * v;
        float ex = __expf(v);
        lsum += ex;
        acc += ex * hs;
    }
    #pragma unroll
    for (int o = 32; o; o >>= 1) {
        lsum += __shfl_xor(lsum, o);
        acc  += __shfl_xor(acc, o);
    }
    if (lane == 0) out[node] = acc / lsum + bf[0];
}

// ---------------- host-side orchestration ----------------

extern "C" void kernel_launch(void* const* d_in, const int* in_sizes, int n_in,
                              void* d_out, int out_size, void* d_ws, size_t ws_size,
                              hipStream_t stream) {
    const float* x  = (const float*)d_in[0];
    const int*   ei = (const int*)d_in[1];
    const float* W0 = (const float*)d_in[3];
    const float* as0 = (const float*)d_in[4];
    const float* ad0 = (const float*)d_in[5];
    const float* b0 = (const float*)d_in[6];
    const float* W1 = (const float*)d_in[7];
    const float* as1 = (const float*)d_in[8];
    const float* ad1 = (const float*)d_in[9];
    const float* b1 = (const float*)d_in[10];
    const float* W2 = (const float*)d_in[11];
    const float* as2 = (const float*)d_in[12];
    const float* ad2 = (const float*)d_in[13];
    const float* b2 = (const float*)d_in[14];
    const float* Wf = (const float*)d_in[15];
    const float* asf = (const float*)d_in[16];
    const float* adf = (const float*)d_in[17];
    const float* bf = (const float*)d_in[18];

    float* out = (float*)d_out;  // 50000 floats

    // workspace carve-up (round-13 layout)
    float* Hf = (float*)d_ws;                    // N*96 float slot: DEG/BS early, XH, then H16
    __half* H16 = (__half*)Hf;
    float* ES = Hf + (long long)N_NODES * HID;   // N
    float* ED = ES + N_NODES;                    // N
    unsigned* RS   = (unsigned*)(ED + N_NODES);  // N+1
    unsigned* WPTR = RS + (N_NODES + 1);         // N
    int* SRCS = (int*)(WPTR + N_NODES);          // E_TOT
    __half* X16A = (__half*)(SRCS + E_TOT + 2);  // N*96 halves (MFMA A + layer-1 residual)
    __half* X16B = X16A + (size_t)N_NODES * HID; // N*96 halves (MFMA A + layer-2 residual)
    __half* WT1 = X16B + (size_t)N_NODES * HID;  // 96*96 halves
    __half* WT2 = WT1 + HID * HID;               // 96*96 halves
    float* HFIN = (float*)(WT2 + HID * HID);     // N floats
    float* AGG  = HFIN + N_NODES;                // N*32 fp32
    unsigned* DEG = (unsigned*)Hf;               // CSR temps aliased onto Hf (pre-prep)
    unsigned* BS  = DEG + N_NODES;
    __half* XH = (__half*)Hf;                    // N*32 fp16 x, aliased onto Hf after CSR

    // ---- CSR build (1-pass hist; XCD-pinned windowed fill) ----
    hipMemsetAsync(DEG, 0, (size_t)N_NODES * sizeof(unsigned), stream);
    const int nb_e = cdiv(E_TOT, 256);
    hist_kernel<<<nb_e, 256, 0, stream>>>(ei, DEG);
    scan_block_kernel<<<N_SCAN_BLOCKS, SCAN_BS, 0, stream>>>(DEG, RS, BS, N_NODES);
    scan_fix_kernel<<<cdiv(N_NODES + 1, 256), 256, 0, stream>>>(RS, BS, WPTR, N_NODES);
    fill_win_kernel<<<nb_e * FILL_PASSES, 256, 0, stream>>>(ei, WPTR, SRCS);

    const int gemm_threads = (N_NODES / 4) * 24;   // 300000
    const int mfma_blocks = cdiv(N_NODES / 16, 4); // 3125 waves -> 782 blocks

    // ---- layer 0: fused prep (+WT transpose), gather, then micro-tiled GEMM ----
    layer0_prep_kernel<<<PREP_BLOCKS + WT_BLOCKS, 256, 0, stream>>>(
        x, W0, as0, ad0, XH, ES, ED, W1, W2, WT1, WT2);
    aggregate32_kernel<<<NODE_BLOCKS, 256, 0, stream>>>(RS, SRCS, ES, ED, XH, AGG);
    gemm32_kernel<<<cdiv(gemm_threads, 256), 256, 0, stream>>>(AGG, W0, b0, X16A);

    // ---- layer 1: X16A -> X16B (residual = X16A fp16), relu ----
    mfma_gemm96_kernel<<<mfma_blocks, 256, 0, stream>>>(X16A, WT1, as1, ad1, H16, ES, ED);
    aggregate96_kernel<<<NODE_BLOCKS, 256, 0, stream>>>(
        RS, SRCS, ES, ED, H16, b1, X16A, X16B, nullptr, nullptr, 1);

    // ---- layer 2: X16B -> HFIN (fused final projection; residual = X16B fp16), relu ----
    mfma_gemm96_kernel<<<mfma_blocks, 256, 0, stream>>>(X16B, WT2, as2, ad2, H16, ES, ED);
    aggregate96_kernel<<<NODE_BLOCKS, 256, 0, stream>>>(
        RS, SRCS, ES, ED, H16, b2, X16B, nullptr, Wf, HFIN, 1);

    // ---- final: HFIN -> out (dout=1) ----
    aggregate1_kernel<<<NODE_BLOCKS, 256, 0, stream>>>(RS, SRCS, HFIN, asf, adf, bf, out);
}